// Round 3
// baseline (28.884 us; speedup 1.0000x reference)
//
#include <hip/hip_runtime.h>

#define MDIM 256
#define BATCH 256
#define NROWS (BATCH * MDIM)          // 65536
#define DIMINISH 0.5f
#define NBLK 1024
#define NTHR 256
#define WAVES_PER_BLK (NTHR / 64)     // 4
#define NWAVES (NBLK * WAVES_PER_BLK) // 4096

// Kernel 1: 4096 waves grid-stride over 65536 rows (16 rows/wave, batch-
// interleaved -> good balance). One wave = one full row: 4 pairs/lane,
// 2x int4 + 2x float4 (32B/lane/array), loads guarded at lane granularity,
// per-pair validity applied as arithmetic mask (no divergent inner branch).
__global__ __launch_bounds__(NTHR) void row_loss_kernel(
    const int*   __restrict__ y_true,
    const float* __restrict__ y_pred,
    const int*   __restrict__ doc_len,
    float*       __restrict__ partial)
{
    const int lane = threadIdx.x & 63;
    const int wid  = threadIdx.x >> 6;
    const int gw   = blockIdx.x * WAVES_PER_BLK + wid;
    const int j0   = lane * 4;                 // first pair index for this lane

    float sum = 0.0f;
    for (int rid = gw; rid < NROWS; rid += NWAVES) {
        const int b  = rid >> 8;               // batch
        const int i  = rid & 255;              // row within batch
        const int dl = doc_len[b];             // L1/L2-resident after warmup
        if (i >= dl || j0 >= dl) continue;     // row-invalid (uniform) / lane tail

        const size_t e = ((size_t)rid * MDIM + (size_t)j0) * 2;  // element offset
        const int4   t0 = *reinterpret_cast<const int4*>(y_true + e);
        const int4   t1 = *reinterpret_cast<const int4*>(y_true + e + 4);
        const float4 p0 = *reinterpret_cast<const float4*>(y_pred + e);
        const float4 p1 = *reinterpret_cast<const float4*>(y_pred + e + 4);

        // pair k layout: flags (neg, pos) = (.x,.y)/(.z,.w); preds likewise
        float s = 0.0f;
        s += ((j0 + 0) < dl ? 1.0f : 0.0f) *
             ((float)t0.y * __logf(p0.y) + DIMINISH * (float)t0.x * __logf(p0.x));
        s += ((j0 + 1) < dl ? 1.0f : 0.0f) *
             ((float)t0.w * __logf(p0.w) + DIMINISH * (float)t0.z * __logf(p0.z));
        s += ((j0 + 2) < dl ? 1.0f : 0.0f) *
             ((float)t1.y * __logf(p1.y) + DIMINISH * (float)t1.x * __logf(p1.x));
        s += ((j0 + 3) < dl ? 1.0f : 0.0f) *
             ((float)t1.w * __logf(p1.w) + DIMINISH * (float)t1.z * __logf(p1.z));
        sum -= s;
    }

    // wave shuffle reduction
    #pragma unroll
    for (int off = 32; off > 0; off >>= 1)
        sum += __shfl_down(sum, off, 64);

    __shared__ float wsum[WAVES_PER_BLK];
    if (lane == 0) wsum[wid] = sum;
    __syncthreads();
    if (threadIdx.x == 0)
        partial[blockIdx.x] = wsum[0] + wsum[1] + wsum[2] + wsum[3];
}

// Kernel 2: deterministic reduction of 1024 partials + doc_len sum.
__global__ __launch_bounds__(1024) void final_reduce_kernel(
    const float* __restrict__ partial,
    const int*   __restrict__ doc_len,
    float*       __restrict__ out)
{
    const int t    = threadIdx.x;
    const int lane = t & 63;
    const int wid  = t >> 6;

    float s = partial[t];                       // NBLK == 1024
    float d = (t < BATCH) ? (float)doc_len[t] : 0.0f;

    #pragma unroll
    for (int off = 32; off > 0; off >>= 1) {
        s += __shfl_down(s, off, 64);
        d += __shfl_down(d, off, 64);
    }

    __shared__ float wsum[16], wdl[16];
    if (lane == 0) { wsum[wid] = s; wdl[wid] = d; }
    __syncthreads();

    if (t < 64) {
        float v  = (t < 16) ? wsum[t] : 0.0f;
        float dv = (t < 16) ? wdl[t]  : 0.0f;
        #pragma unroll
        for (int off = 8; off > 0; off >>= 1) {
            v  += __shfl_down(v, off, 64);
            dv += __shfl_down(dv, off, 64);
        }
        if (t == 0) out[0] = v / dv;
    }
}

extern "C" void kernel_launch(void* const* d_in, const int* in_sizes, int n_in,
                              void* d_out, int out_size, void* d_ws, size_t ws_size,
                              hipStream_t stream)
{
    const int*   y_true  = (const int*)d_in[0];   // (B, M*M, 2) int32
    const float* y_pred  = (const float*)d_in[1]; // (B, M*M, 2) float32
    const int*   doc_len = (const int*)d_in[2];   // (B,) int32
    float*       out     = (float*)d_out;
    float*       partial = (float*)d_ws;          // 1024 floats = 4 KB

    row_loss_kernel<<<NBLK, NTHR, 0, stream>>>(y_true, y_pred, doc_len, partial);
    final_reduce_kernel<<<1, 1024, 0, stream>>>(partial, doc_len, out);
}